// Round 17
// baseline (115.259 us; speedup 1.0000x reference)
//
#include <hip/hip_runtime.h>

#define Gg   32
#define Nn   128
#define Hh   128
#define Ee   65536
#define GN   4096      // Gg*Nn
#define GNN  524288    // Gg*Nn*Nn

typedef unsigned short ushort_t;
typedef __attribute__((ext_vector_type(8))) __bf16 bf16x8;
typedef __attribute__((ext_vector_type(4))) float f32x4;
struct us4 { ushort_t a, b, c, d; };

__device__ __forceinline__ float reluf(float x) { return x > 0.f ? x : 0.f; }

// monotone float <-> u32 key (for atomicMax on floats incl. negatives)
__device__ __forceinline__ unsigned fkey(float f) {
  unsigned u = __float_as_uint(f);
  return (u & 0x80000000u) ? ~u : (u | 0x80000000u);
}
__device__ __forceinline__ float funkey(unsigned k) {
  unsigned u = (k & 0x80000000u) ? (k ^ 0x80000000u) : ~k;
  return __uint_as_float(u);
}

// round-to-nearest-even f32 -> bf16 bits
__device__ __forceinline__ ushort_t bfh(float x) {
  unsigned u = __float_as_uint(x);
  return (ushort_t)((u + 0x7FFFu + ((u >> 16) & 1u)) >> 16);
}
__device__ __forceinline__ void split2(float x, ushort_t& h, ushort_t& l) {
  h = bfh(x);
  float hf = __uint_as_float(((unsigned)h) << 16);
  l = bfh(x - hf);
}

// ---------------- phase 1: weight prep (wt+wo+wm) + win fill + me2, ONE launch --
// fragment order: element (n,k): nf=n>>4, lr=n&15, kf=k>>5, lg=(k>>3)&3, j=k&7
// off = ((nf*KCH + kf)*64 + lg*16 + lr)*8 + j
__global__ __launch_bounds__(256) void k_wprep_all(const float* __restrict__ W_h1,
                                                   const float* __restrict__ W_h2,
                                                   const float* __restrict__ W_o1,
                                                   const float* __restrict__ W_o2,
                                                   const float* __restrict__ W_m1,
                                                   const float* __restrict__ W_m2,
                                                   const float* __restrict__ bond_tab,
                                                   const float* __restrict__ W_me,
                                                   const float* __restrict__ b_me,
                                                   const float* __restrict__ b_mg,
                                                   ushort_t* __restrict__ wt,
                                                   ushort_t* __restrict__ wo,
                                                   ushort_t* __restrict__ wm,
                                                   int* __restrict__ win,
                                                   float* __restrict__ me0,
                                                   float* __restrict__ me1,
                                                   unsigned* __restrict__ aggkA,
                                                   unsigned* __restrict__ aggkB) {
  int b = blockIdx.x;
  int tid = threadIdx.x;
  if (b < 256) {                       // wt: 2l*2m*16384, KCH=4
    int t = b * 256 + tid;
    int l = t >> 15;
    int m = (t >> 14) & 1;
    int e = t & 16383;
    int n = e & 127, k = e >> 7;
    const float* W = (m == 0 ? W_h1 : W_h2) + l * 16384;
    float v = W[k * 128 + n];
    ushort_t h, lo;
    split2(v, h, lo);
    int nf = n >> 4, lr = n & 15, kf = k >> 5, lg = (k >> 3) & 3, j = k & 7;
    int off = ((nf * 4 + kf) * 64 + lg * 16 + lr) * 8 + j;
    int base = ((l * 2 + m) * 2) * 16384;
    wt[base + off] = h;
    wt[base + 16384 + off] = lo;
  } else if (b < 640) {                // wo: 2l*49152, KCH=12
    int ep = (b - 256) * 256 + tid;
    int l = (ep >= 49152) ? 1 : 0;
    int e = ep - l * 49152;
    int n = e / 384, k = e - n * 384;
    float v = (k < 256) ? W_o1[(l * 256 + k) * 128 + n]
                        : W_o2[(l * 128 + (k - 256)) * 128 + n];
    ushort_t h, lo;
    split2(v, h, lo);
    int nf = n >> 4, lr = n & 15, kf = k >> 5, lg = (k >> 3) & 3, j = k & 7;
    int off = ((nf * 12 + kf) * 64 + lg * 16 + lr) * 8 + j;
    wo[(l * 2 + 0) * 49152 + off] = h;
    wo[(l * 2 + 1) * 49152 + off] = lo;
  } else if (b < 1152) {               // wm: 2l*2m*32768, KCH=8
    int t = (b - 640) * 256 + tid;
    int l = t >> 16;
    int m = (t >> 15) & 1;
    int e = t & 32767;
    int n = e >> 8, k = e & 255;
    const float* W = (m == 0 ? W_m1 : W_m2);
    float v = W[(l * 256 + k) * 128 + n];
    ushort_t h, lo;
    split2(v, h, lo);
    int nf = n >> 4, lr = n & 15, kf = k >> 5, lg = (k >> 3) & 3, j = k & 7;
    int off = ((nf * 8 + kf) * 64 + lg * 16 + lr) * 8 + j;
    int base = ((l * 2 + m) * 2) * 32768;
    wm[base + off] = h;
    wm[base + 32768 + off] = lo;
  } else if (b < 1664) {               // win = -1 (131072 int4s = 2MB)
    int idx = (b - 1152) * 256 + tid;
    ((int4*)win)[idx] = make_int4(-1, -1, -1, -1);
  } else {                             // me tables + aggk inits (512 blocks)
    int bx = b - 1664;
    int l = bx >> 8, b2 = bx & 255;
    const float* W = W_me + l * 16384;
    const float* bme = b_me + l * 128;
    const float* bmg = b_mg + l * 128;
    float* me = l ? me1 : me0;
    unsigned* aggk = l ? aggkB : aggkA;
    __shared__ float v[2][128];
    int half = tid >> 7, j = tid & 127;
    int c = b2 * 2 + half;
    int a0 = c & 7, a1 = (c >> 3) & 7, a2 = (c >> 6) & 7;
    v[half][j] = bond_tab[a0 * 128 + j] + bond_tab[(8 + a1) * 128 + j] +
                 bond_tab[(16 + a2) * 128 + j];
    __syncthreads();
    float acc = bme[j] + bmg[j];
    for (int i = 0; i < 128; ++i) acc += v[half][i] * W[i * 128 + j];
    me[c * 128 + j] = acc;
    unsigned key = fkey(-1.0e9f);
#pragma unroll
    for (int i = 0; i < 8; ++i) aggk[b2 * 2048 + i * 256 + tid] = key;
  }
}

// ---------------- MFMA A-fragment helpers ----------------
__device__ __forceinline__ void load_afrag(const ushort_t (*MH)[136],
                                           const ushort_t (*ML)[136],
                                           int row, int lg,
                                           bf16x8 ah[4], bf16x8 al[4]) {
#pragma unroll
  for (int kf = 0; kf < 4; ++kf) {
    ah[kf] = *(const bf16x8*)&MH[row][lg * 8 + 32 * kf];
    al[kf] = *(const bf16x8*)&ML[row][lg * 8 + 32 * kf];
  }
}

__device__ __forceinline__ void load_afrag264(const ushort_t (*MH)[264],
                                              const ushort_t (*ML)[264],
                                              int row, int base, int lg,
                                              bf16x8 ah[4], bf16x8 al[4]) {
#pragma unroll
  for (int kf = 0; kf < 4; ++kf) {
    ah[kf] = *(const bf16x8*)&MH[row][base + lg * 8 + 32 * kf];
    al[kf] = *(const bf16x8*)&ML[row][base + lg * 8 + 32 * kf];
  }
}

// ---------------- phase 2: node-encode+m12 (b<256) + edge scatter (b>=256) ------
__global__ __launch_bounds__(256) void k_pre2(const int* __restrict__ x,
                                              const float* __restrict__ atom_tab,
                                              const ushort_t* __restrict__ wm,
                                              const float* __restrict__ bi1,
                                              const float* __restrict__ bi2,
                                              float* __restrict__ nf_,
                                              float* __restrict__ hid,
                                              float* __restrict__ m1,
                                              float* __restrict__ m2,
                                              const int* __restrict__ e32,
                                              int* __restrict__ win) {
  int b = blockIdx.x;
  int tid = threadIdx.x;
  if (b >= 256) {                     // ---- edge winner scatter ----
    __shared__ int sflag;
    if (tid == 0) sflag = 0;
    __syncthreads();
    if (tid < 128 && e32[2 * tid + 1] != 0) atomicOr(&sflag, 1);
    __syncthreads();
    int e = (b - 256) * 256 + tid;
    int sg, dg;
    if (sflag) { sg = e32[e]; dg = e32[Ee + e]; }        // int32 layout
    else       { sg = e32[2 * e]; dg = e32[2 * Ee + 2 * e]; }  // int64 low words
    int g = sg / Nn;
    int s = sg % Nn;
    int d = dg % Nn;
    atomicMax(&win[(g * Nn + d) * Nn + s], e);   // destination-major
    return;
  }
  // ---- node encode + layer-0 m12 (hid0=0 => seg0 only) ----
  __shared__ ushort_t AH[16][136];
  __shared__ ushort_t AL[16][136];
  __shared__ int xs[144];
  int v0 = b * 16;
  if (tid < 144) xs[tid] = x[v0 * 9 + tid];
  __syncthreads();
#pragma unroll
  for (int i = 0; i < 8; ++i) {
    int e = tid + i * 256;
    int row = e >> 7, col = e & 127;
    float s = 0.f;
#pragma unroll
    for (int f = 0; f < 9; ++f) {
      int idx = xs[row * 9 + f];
      s += atom_tab[(f * 119 + idx) * Hh + col];
    }
    nf_[(v0 + row) * Hh + col] = s;
    hid[(v0 + row) * Hh + col] = 0.f;
    ushort_t h, l;
    split2(s, h, l);
    AH[row][col] = h;
    AL[row][col] = l;
  }
  __syncthreads();
  int lane = tid & 63, wid = tid >> 6;
  int lr = lane & 15, lg = lane >> 4;
  f32x4 a1[2], a2[2];
#pragma unroll
  for (int i = 0; i < 2; ++i) { a1[i] = (f32x4){0.f,0.f,0.f,0.f}; a2[i] = (f32x4){0.f,0.f,0.f,0.f}; }
  const ushort_t* w1h = wm;
  const ushort_t* w1l = wm + 32768;
  const ushort_t* w2h = wm + 65536;
  const ushort_t* w2l = wm + 98304;
  bf16x8 ah[4], al[4];
  load_afrag(AH, AL, lr, lg, ah, al);
#pragma unroll
  for (int jj = 0; jj < 2; ++jj) {
    int nfr = 2 * wid + jj;
#pragma unroll
    for (int kf = 0; kf < 4; ++kf) {            // seg 0 only (hid = 0)
      int ch = ((nfr * 8 + kf) << 9) + lane * 8;
      bf16x8 b1h = *(const bf16x8*)(w1h + ch);
      bf16x8 b1l = *(const bf16x8*)(w1l + ch);
      bf16x8 b2h = *(const bf16x8*)(w2h + ch);
      bf16x8 b2l = *(const bf16x8*)(w2l + ch);
      a1[jj] = __builtin_amdgcn_mfma_f32_16x16x32_bf16(ah[kf], b1h, a1[jj], 0, 0, 0);
      a1[jj] = __builtin_amdgcn_mfma_f32_16x16x32_bf16(ah[kf], b1l, a1[jj], 0, 0, 0);
      a1[jj] = __builtin_amdgcn_mfma_f32_16x16x32_bf16(al[kf], b1h, a1[jj], 0, 0, 0);
      a2[jj] = __builtin_amdgcn_mfma_f32_16x16x32_bf16(ah[kf], b2h, a2[jj], 0, 0, 0);
      a2[jj] = __builtin_amdgcn_mfma_f32_16x16x32_bf16(ah[kf], b2l, a2[jj], 0, 0, 0);
      a2[jj] = __builtin_amdgcn_mfma_f32_16x16x32_bf16(al[kf], b2h, a2[jj], 0, 0, 0);
    }
  }
#pragma unroll
  for (int jj = 0; jj < 2; ++jj) {
    int col = 16 * (2 * wid + jj) + lr;
    float bb1 = bi1[col], bb2 = bi2[col];
#pragma unroll
    for (int reg = 0; reg < 4; ++reg) {
      int row = v0 + lg * 4 + reg;
      m1[row * Hh + col] = a1[jj][reg] + bb1;
      m2[row * Hh + col] = a2[jj][reg] + bb2;
    }
  }
}

// ---------------- per-destination compaction: count / scan / fill ----------------
__global__ __launch_bounds__(256) void k_dcount(const int* __restrict__ win,
                                                int* __restrict__ dcnt) {
  int tid = threadIdx.x;
  int grp = tid >> 7, t = tid & 127;
  int dest = blockIdx.x * 2 + grp;
  bool valid = win[dest * 128 + t] >= 0;
  unsigned long long mask = __ballot(valid);
  __shared__ int cw[4];
  if ((tid & 63) == 0) cw[tid >> 6] = __popcll(mask);
  __syncthreads();
  if (t == 0) dcnt[dest] = cw[grp * 2] + cw[grp * 2 + 1];
}

__global__ __launch_bounds__(512) void k_dscan(const int* __restrict__ dcnt,
                                               int* __restrict__ rowptr) {
  int tid = threadIdx.x;            // 512 threads x 8 dests = 4096
  int c0, c1, c2, c3, c4, c5, c6, c7;
  int bi = tid * 8;
  c0 = dcnt[bi + 0]; c1 = dcnt[bi + 1]; c2 = dcnt[bi + 2]; c3 = dcnt[bi + 3];
  c4 = dcnt[bi + 4]; c5 = dcnt[bi + 5]; c6 = dcnt[bi + 6]; c7 = dcnt[bi + 7];
  int s = c0 + c1 + c2 + c3 + c4 + c5 + c6 + c7;
  int x = s;
#pragma unroll
  for (int off = 1; off < 64; off <<= 1) {
    int y = __shfl_up(x, off, 64);
    if ((tid & 63) >= off) x += y;
  }
  __shared__ int wsum[8], woff[8];
  if ((tid & 63) == 63) wsum[tid >> 6] = x;
  __syncthreads();
  if (tid == 0) {
    int a = 0;
#pragma unroll
    for (int i = 0; i < 8; ++i) { woff[i] = a; a += wsum[i]; }
  }
  __syncthreads();
  int base = x - s + woff[tid >> 6];
  rowptr[bi + 0] = base; base += c0;
  rowptr[bi + 1] = base; base += c1;
  rowptr[bi + 2] = base; base += c2;
  rowptr[bi + 3] = base; base += c3;
  rowptr[bi + 4] = base; base += c4;
  rowptr[bi + 5] = base; base += c5;
  rowptr[bi + 6] = base; base += c6;
  rowptr[bi + 7] = base; base += c7;
  if (tid == 511) rowptr[4096] = base;   // total count
}

__global__ __launch_bounds__(256) void k_dfill(const int* __restrict__ win,
                                               const int* __restrict__ eattr,
                                               const int* __restrict__ rowptr,
                                               unsigned* __restrict__ recs) {
  int tid = threadIdx.x;
  int grp = tid >> 7, t = tid & 127;
  int dest = blockIdx.x * 2 + grp;
  int e = win[dest * 128 + t];
  bool valid = e >= 0;
  unsigned long long mask = __ballot(valid);
  __shared__ int cw[4];
  int lane = tid & 63;
  if (lane == 0) cw[tid >> 6] = __popcll(mask);
  __syncthreads();
  if (valid) {
    int off = __popcll(mask & ((1ull << lane) - 1));
    if ((tid >> 6) & 1) off += cw[grp * 2];
    int a0 = eattr[e * 3 + 0], a1 = eattr[e * 3 + 1], a2 = eattr[e * 3 + 2];
    unsigned code = (unsigned)(a0 + (a1 << 3) + (a2 << 6));
    unsigned idx = ((unsigned)dest << 7) | (unsigned)t;   // (g*128+d)*128+s
    recs[rowptr[dest] + off] = (idx << 9) | code;         // sorted by dest
  }
}

// ---------------- edge phase: 64-edge tile, 8 waves (1 col-group each) ----------
__global__ __launch_bounds__(512) void k_edge(const unsigned* __restrict__ recs,
                                              const int* __restrict__ cnt,
                                              const float* __restrict__ m1,
                                              const float* __restrict__ m2,
                                              const float* __restrict__ me,
                                              const ushort_t* __restrict__ wt1h,
                                              const ushort_t* __restrict__ wt1l,
                                              const ushort_t* __restrict__ wt2h,
                                              const ushort_t* __restrict__ wt2l,
                                              const float* __restrict__ b_h1,
                                              const float* __restrict__ b_h2,
                                              unsigned* __restrict__ aggk) {
  __shared__ ushort_t MH[64][136];
  __shared__ ushort_t ML[64][136];
  __shared__ unsigned srec[64];
  int tid = threadIdx.x;
  int n = *cnt;
  if ((int)(blockIdx.x * 64) >= n) return;   // empty tile: nothing to aggregate
  if (tid < 64) {
    int r = blockIdx.x * 64 + tid;
    srec[tid] = (r < n) ? recs[r] : 0xFFFFFFFFu;
  }
  __syncthreads();
  // build M tile (float4-vectorized; 512 threads cover 64 rows x 32 col4)
  {
    int c4 = tid & 31, rq = tid >> 5;     // rq in 0..15
#pragma unroll
    for (int i = 0; i < 4; ++i) {
      int r = 16 * i + rq;
      float4 v = make_float4(0.f, 0.f, 0.f, 0.f);
      unsigned rec = srec[r];
      if (rec != 0xFFFFFFFFu) {
        int code = rec & 511;
        unsigned idx = rec >> 9;
        int s = idx & 127, d = (idx >> 7) & 127, g = idx >> 14;
        float4 a = *(const float4*)(m1 + (((g << 7) + d) << 7) + c4 * 4);
        float4 b = *(const float4*)(m2 + (((g << 7) + s) << 7) + c4 * 4);
        float4 cme = *(const float4*)(me + (code << 7) + c4 * 4);
        v.x = reluf(a.x + b.x + cme.x);
        v.y = reluf(a.y + b.y + cme.y);
        v.z = reluf(a.z + b.z + cme.z);
        v.w = reluf(a.w + b.w + cme.w);
      }
      us4 h4, l4;
      split2(v.x, h4.a, l4.a); split2(v.y, h4.b, l4.b);
      split2(v.z, h4.c, l4.c); split2(v.w, h4.d, l4.d);
      *(us4*)&MH[r][c4 * 4] = h4;
      *(us4*)&ML[r][c4 * 4] = l4;
    }
  }
  __syncthreads();

  int lane = tid & 63, wid = tid >> 6;     // wid = nf (0..7)
  int lr = lane & 15, lg = lane >> 4;
  float b1v = b_h1[16 * wid + lr];
  float b2v = b_h2[16 * wid + lr];
  f32x4 acc[4];
#pragma unroll
  for (int rg = 0; rg < 4; ++rg) acc[rg] = (f32x4){0.f, 0.f, 0.f, 0.f};
  // GEMM1: wave computes all 64 rows x its 16 cols (nf = wid)
#pragma unroll
  for (int rg = 0; rg < 4; ++rg) {
    bf16x8 ah[4], al[4];
    load_afrag(MH, ML, 16 * rg + lr, lg, ah, al);
#pragma unroll
    for (int kf = 0; kf < 4; ++kf) {
      int ch = ((wid * 4 + kf) << 9) + lane * 8;
      bf16x8 bh = *(const bf16x8*)(wt1h + ch);
      bf16x8 bl = *(const bf16x8*)(wt1l + ch);
      acc[rg] = __builtin_amdgcn_mfma_f32_16x16x32_bf16(ah[kf], bh, acc[rg], 0, 0, 0);
      acc[rg] = __builtin_amdgcn_mfma_f32_16x16x32_bf16(ah[kf], bl, acc[rg], 0, 0, 0);
      acc[rg] = __builtin_amdgcn_mfma_f32_16x16x32_bf16(al[kf], bh, acc[rg], 0, 0, 0);
    }
  }
  // prefetch GEMM2 B fragments now (A-fragment regs are dead; overlaps T phase)
  bf16x8 B2h[4], B2l[4];
#pragma unroll
  for (int kf = 0; kf < 4; ++kf) {
    int ch = ((wid * 4 + kf) << 9) + lane * 8;
    B2h[kf] = *(const bf16x8*)(wt2h + ch);
    B2l[kf] = *(const bf16x8*)(wt2l + ch);
  }
  __syncthreads();   // M fully consumed by all waves
  // T = relu(acc + b1) -> MH/ML
#pragma unroll
  for (int rg = 0; rg < 4; ++rg)
#pragma unroll
    for (int reg = 0; reg < 4; ++reg) {
      float t = reluf(acc[rg][reg] + b1v);
      int row = 16 * rg + lg * 4 + reg;
      int col = 16 * wid + lr;
      ushort_t h, l;
      split2(t, h, l);
      MH[row][col] = h;
      ML[row][col] = l;
    }
  __syncthreads();   // T complete
  // GEMM2 (B fragments already in registers)
#pragma unroll
  for (int rg = 0; rg < 4; ++rg) acc[rg] = (f32x4){0.f, 0.f, 0.f, 0.f};
#pragma unroll
  for (int rg = 0; rg < 4; ++rg) {
    bf16x8 ah[4], al[4];
    load_afrag(MH, ML, 16 * rg + lr, lg, ah, al);
#pragma unroll
    for (int kf = 0; kf < 4; ++kf) {
      acc[rg] = __builtin_amdgcn_mfma_f32_16x16x32_bf16(ah[kf], B2h[kf], acc[rg], 0, 0, 0);
      acc[rg] = __builtin_amdgcn_mfma_f32_16x16x32_bf16(ah[kf], B2l[kf], acc[rg], 0, 0, 0);
      acc[rg] = __builtin_amdgcn_mfma_f32_16x16x32_bf16(al[kf], B2h[kf], acc[rg], 0, 0, 0);
    }
  }
  __syncthreads();   // T fully consumed
  // park f32 result bits in MH/ML (wave-own columns)
#pragma unroll
  for (int rg = 0; rg < 4; ++rg)
#pragma unroll
    for (int reg = 0; reg < 4; ++reg) {
      int row = 16 * rg + lg * 4 + reg;
      int col = 16 * wid + lr;
      unsigned b = __float_as_uint(acc[rg][reg] + b2v);
      MH[row][col] = (ushort_t)(b >> 16);
      ML[row][col] = (ushort_t)(b & 0xFFFFu);
    }
  // wave-local scan (reads only this wave's parked columns -> no barrier needed)
  {
    int col = 16 * wid + (lane & 15);
    int quarter = lane >> 4;                 // 4 x 16-row segments
    int rbeg = quarter * 16, rend = rbeg + 16;
    unsigned curkey = 0xFFFFu;
    float best = -3.0e38f;
    for (int r = rbeg; r < rend; ++r) {
      unsigned rec = srec[r];
      unsigned key = rec >> 16;   // g*128+d (<=0xFFF) or 0xFFFF if invalid
      if (key != curkey) {
        if (curkey != 0xFFFFu)
          atomicMax(aggk + (curkey << 7) + col, fkey(best));
        curkey = key;
        best = -3.0e38f;
      }
      if (key != 0xFFFFu) {
        unsigned b = ((unsigned)MH[r][col] << 16) | (unsigned)ML[r][col];
        best = fmaxf(best, __uint_as_float(b));
      }
    }
    if (curkey != 0xFFFFu)
      atomicMax(aggk + (curkey << 7) + col, fkey(best));
  }
}

// ---------------- hid update via MFMA (plain, for last layer) ----------------
__global__ __launch_bounds__(256) void k_out(const float* __restrict__ nf,
                                             const float* __restrict__ hid,
                                             const unsigned* __restrict__ aggk,
                                             const ushort_t* __restrict__ wo_h,
                                             const ushort_t* __restrict__ wo_l,
                                             const float* __restrict__ bo1,
                                             const float* __restrict__ bo2,
                                             float* __restrict__ hidn) {
  __shared__ ushort_t MH[16][136];
  __shared__ ushort_t ML[16][136];
  int tid = threadIdx.x;
  int v0 = blockIdx.x * 16;
  int lane = tid & 63, wid = tid >> 6;
  int lr = lane & 15, lg = lane >> 4;
  f32x4 acc[2];
#pragma unroll
  for (int jj = 0; jj < 2; ++jj) acc[jj] = (f32x4){0.f, 0.f, 0.f, 0.f};

  for (int seg = 0; seg < 3; ++seg) {
#pragma unroll
    for (int i = 0; i < 2; ++i) {
      int idx = tid + i * 256;        // over 512 float4s
      int row = idx >> 5, c4 = idx & 31;
      float4 v;
      if (seg == 0)      v = ((const float4*)nf)[(v0 + row) * 32 + c4];
      else if (seg == 1) v = ((const float4*)hid)[(v0 + row) * 32 + c4];
      else {
        uint4 k4 = ((const uint4*)aggk)[(v0 + row) * 32 + c4];
        v.x = funkey(k4.x); v.y = funkey(k4.y); v.z = funkey(k4.z); v.w = funkey(k4.w);
      }
      us4 h4, l4;
      split2(v.x, h4.a, l4.a);
      split2(v.y, h4.b, l4.b);
      split2(v.z, h4.c, l4.c);
      split2(v.w, h4.d, l4.d);
      *(us4*)&MH[row][c4 * 4] = h4;
      *(us4*)&ML[row][c4 * 4] = l4;
    }
    __syncthreads();
    bf16x8 ah[4], al[4];
    load_afrag(MH, ML, lr, lg, ah, al);
#pragma unroll
    for (int jj = 0; jj < 2; ++jj) {
      int nfr = 2 * wid + jj;
#pragma unroll
      for (int kf = 0; kf < 4; ++kf) {
        int ch = ((nfr * 12 + seg * 4 + kf) << 9) + lane * 8;
        bf16x8 bh = *(const bf16x8*)(wo_h + ch);
        bf16x8 bl = *(const bf16x8*)(wo_l + ch);
        acc[jj] = __builtin_amdgcn_mfma_f32_16x16x32_bf16(ah[kf], bh, acc[jj], 0, 0, 0);
        acc[jj] = __builtin_amdgcn_mfma_f32_16x16x32_bf16(ah[kf], bl, acc[jj], 0, 0, 0);
        acc[jj] = __builtin_amdgcn_mfma_f32_16x16x32_bf16(al[kf], bh, acc[jj], 0, 0, 0);
      }
    }
    __syncthreads();
  }
#pragma unroll
  for (int jj = 0; jj < 2; ++jj) {
    int col = 16 * (2 * wid + jj) + lr;
    float b = bo1[col] + bo2[col];
#pragma unroll
    for (int reg = 0; reg < 4; ++reg)
      hidn[(v0 + lg * 4 + reg) * Hh + col] = reluf(acc[jj][reg] + b);
  }
}

// ---------------- hid update + next-layer m12 fused (for layer transition) -----
__global__ __launch_bounds__(256) void k_out_m12(const float* __restrict__ nf,
                                                 const float* __restrict__ hid,
                                                 const unsigned* __restrict__ aggk,
                                                 const ushort_t* __restrict__ wo_h,
                                                 const ushort_t* __restrict__ wo_l,
                                                 const float* __restrict__ bo1,
                                                 const float* __restrict__ bo2,
                                                 const ushort_t* __restrict__ wm,
                                                 const float* __restrict__ bm1,
                                                 const float* __restrict__ bm2,
                                                 float* __restrict__ hidn,
                                                 float* __restrict__ m1,
                                                 float* __restrict__ m2) {
  __shared__ ushort_t AH[16][264];
  __shared__ ushort_t AL[16][264];
  int tid = threadIdx.x;
  int v0 = blockIdx.x * 16;
  int lane = tid & 63, wid = tid >> 6;
  int lr = lane & 15, lg = lane >> 4;
  f32x4 acc[2];
#pragma unroll
  for (int jj = 0; jj < 2; ++jj) acc[jj] = (f32x4){0.f, 0.f, 0.f, 0.f};

  // phase 1: hidn = relu([nf|hid|agg] @ Wo + b)
  for (int seg = 0; seg < 3; ++seg) {
#pragma unroll
    for (int i = 0; i < 2; ++i) {
      int idx = tid + i * 256;
      int row = idx >> 5, c4 = idx & 31;
      float4 v;
      if (seg == 0)      v = ((const float4*)nf)[(v0 + row) * 32 + c4];
      else if (seg == 1) v = ((const float4*)hid)[(v0 + row) * 32 + c4];
      else {
        uint4 k4 = ((const uint4*)aggk)[(v0 + row) * 32 + c4];
        v.x = funkey(k4.x); v.y = funkey(k4.y); v.z = funkey(k4.z); v.w = funkey(k4.w);
      }
      us4 h4, l4;
      split2(v.x, h4.a, l4.a);
      split2(v.y, h4.b, l4.b);
      split2(v.z, h4.c, l4.c);
      split2(v.w, h4.d, l4.d);
      *(us4*)&AH[row][c4 * 4] = h4;
      *(us4*)&AL[row][c4 * 4] = l4;
    }
    __syncthreads();
    bf16x8 ah[4], al[4];
    load_afrag264(AH, AL, lr, 0, lg, ah, al);
#pragma unroll
    for (int jj = 0; jj < 2; ++jj) {
      int nfr = 2 * wid + jj;
#pragma unroll
      for (int kf = 0; kf < 4; ++kf) {
        int ch = ((nfr * 12 + seg * 4 + kf) << 9) + lane * 8;
        bf16x8 bh = *(const bf16x8*)(wo_h + ch);
        bf16x8 bl = *(const bf16x8*)(wo_l + ch);
        acc[jj] = __builtin_amdgcn_mfma_f32_16x16x32_bf16(ah[kf], bh, acc[jj], 0, 0, 0);
        acc[jj] = __builtin_amdgcn_mfma_f32_16x16x32_bf16(ah[kf], bl, acc[jj], 0, 0, 0);
        acc[jj] = __builtin_amdgcn_mfma_f32_16x16x32_bf16(al[kf], bh, acc[jj], 0, 0, 0);
      }
    }
    __syncthreads();
  }
  // write hidn + stage hidn into cols 128..255
#pragma unroll
  for (int jj = 0; jj < 2; ++jj) {
    int col = 16 * (2 * wid + jj) + lr;
    float b = bo1[col] + bo2[col];
#pragma unroll
    for (int reg = 0; reg < 4; ++reg) {
      float hv = reluf(acc[jj][reg] + b);
      int row = lg * 4 + reg;
      hidn[(v0 + row) * Hh + col] = hv;
      ushort_t h, l;
      split2(hv, h, l);
      AH[row][128 + col] = h;
      AL[row][128 + col] = l;
    }
  }
  // stage nf into cols 0..127
#pragma unroll
  for (int i = 0; i < 2; ++i) {
    int idx = tid + i * 256;
    int row = idx >> 5, c4 = idx & 31;
    float4 v = ((const float4*)nf)[(v0 + row) * 32 + c4];
    us4 h4, l4;
    split2(v.x, h4.a, l4.a);
    split2(v.y, h4.b, l4.b);
    split2(v.z, h4.c, l4.c);
    split2(v.w, h4.d, l4.d);
    *(us4*)&AH[row][c4 * 4] = h4;
    *(us4*)&AL[row][c4 * 4] = l4;
  }
  __syncthreads();
  // phase 2: m1/m2 = [nf|hidn] @ W_m + b (2 segs)
  f32x4 a1[2], a2[2];
#pragma unroll
  for (int i = 0; i < 2; ++i) { a1[i] = (f32x4){0.f,0.f,0.f,0.f}; a2[i] = (f32x4){0.f,0.f,0.f,0.f}; }
  const ushort_t* w1h = wm;
  const ushort_t* w1l = wm + 32768;
  const ushort_t* w2h = wm + 65536;
  const ushort_t* w2l = wm + 98304;
#pragma unroll
  for (int seg = 0; seg < 2; ++seg) {
    bf16x8 ah[4], al[4];
    load_afrag264(AH, AL, lr, seg * 128, lg, ah, al);
#pragma unroll
    for (int jj = 0; jj < 2; ++jj) {
      int nfr = 2 * wid + jj;
#pragma unroll
      for (int kf = 0; kf < 4; ++kf) {
        int ch = ((nfr * 8 + seg * 4 + kf) << 9) + lane * 8;
        bf16x8 b1h = *(const bf16x8*)(w1h + ch);
        bf16x8 b1l = *(const bf16x8*)(w1l + ch);
        bf16x8 b2h = *(const bf16x8*)(w2h + ch);
        bf16x8 b2l = *(const bf16x8*)(w2l + ch);
        a1[jj] = __builtin_amdgcn_mfma_f32_16x16x32_bf16(ah[kf], b1h, a1[jj], 0, 0, 0);
        a1[jj] = __builtin_amdgcn_mfma_f32_16x16x32_bf16(ah[kf], b1l, a1[jj], 0, 0, 0);
        a1[jj] = __builtin_amdgcn_mfma_f32_16x16x32_bf16(al[kf], b1h, a1[jj], 0, 0, 0);
        a2[jj] = __builtin_amdgcn_mfma_f32_16x16x32_bf16(ah[kf], b2h, a2[jj], 0, 0, 0);
        a2[jj] = __builtin_amdgcn_mfma_f32_16x16x32_bf16(ah[kf], b2l, a2[jj], 0, 0, 0);
        a2[jj] = __builtin_amdgcn_mfma_f32_16x16x32_bf16(al[kf], b2h, a2[jj], 0, 0, 0);
      }
    }
  }
#pragma unroll
  for (int jj = 0; jj < 2; ++jj) {
    int col = 16 * (2 * wid + jj) + lr;
    float bb1 = bm1[col], bb2 = bm2[col];
#pragma unroll
    for (int reg = 0; reg < 4; ++reg) {
      int row = v0 + lg * 4 + reg;
      m1[row * Hh + col] = a1[jj][reg] + bb1;
      m2[row * Hh + col] = a2[jj][reg] + bb2;
    }
  }
}

// ---------------- readout head ----------------
__global__ __launch_bounds__(128) void k_head(const float* __restrict__ hid,
                                              const float* __restrict__ Wg1,
                                              const float* __restrict__ bg1,
                                              const float* __restrict__ Wg2,
                                              const float* __restrict__ bg2,
                                              float* __restrict__ out) {
  __shared__ float emb[Hh];
  __shared__ float tt[Hh];
  int g = blockIdx.x, j = threadIdx.x;
  float s = 0.f;
  for (int n = 0; n < Nn; ++n) s += hid[(g * Nn + n) * Hh + j];
  emb[j] = s * (1.f / Nn);
  __syncthreads();
  float a = bg1[j];
  for (int i = 0; i < Hh; ++i) a += emb[i] * Wg1[i * Hh + j];
  tt[j] = reluf(a);
  __syncthreads();
  if (j < 12) {
    float o = bg2[j];
    for (int i = 0; i < Hh; ++i) o += tt[i] * Wg2[i * 12 + j];
    out[g * 12 + j] = o;
  }
}

extern "C" void kernel_launch(void* const* d_in, const int* in_sizes, int n_in,
                              void* d_out, int out_size, void* d_ws, size_t ws_size,
                              hipStream_t stream) {
  const int* x = (const int*)d_in[0];
  const int* eidx32 = (const int*)d_in[1];
  const int* eattr = (const int*)d_in[2];
  const float* atom_tab = (const float*)d_in[4];
  const float* bond_tab = (const float*)d_in[5];
  const float* W_m1 = (const float*)d_in[6];
  const float* b_m1 = (const float*)d_in[7];
  const float* W_m2 = (const float*)d_in[8];
  const float* b_m2 = (const float*)d_in[9];
  const float* W_me = (const float*)d_in[10];
  const float* b_me = (const float*)d_in[11];
  const float* b_mg = (const float*)d_in[13];
  const float* W_h1 = (const float*)d_in[14];
  const float* b_h1 = (const float*)d_in[15];
  const float* W_h2 = (const float*)d_in[16];
  const float* b_h2 = (const float*)d_in[17];
  const float* W_o1 = (const float*)d_in[18];
  const float* b_o1 = (const float*)d_in[19];
  const float* W_o2 = (const float*)d_in[20];
  const float* b_o2 = (const float*)d_in[21];
  const float* Wg1 = (const float*)d_in[22];
  const float* bg1 = (const float*)d_in[23];
  const float* Wg2 = (const float*)d_in[24];
  const float* bg2 = (const float*)d_in[25];
  float* out = (float*)d_out;

  char* ws = (char*)d_ws;
  float* nf = (float*)(ws);                                 // 2MB
  float* hidA = (float*)(ws + (2u << 20));                  // 2MB (hid0 zeros, hid2)
  float* hidB = (float*)(ws + (4u << 20));                  // 2MB (hid1)
  float* m1 = (float*)(ws + (6u << 20));                    // 2MB
  float* m2 = (float*)(ws + (8u << 20));                    // 2MB
  unsigned* aggkA = (unsigned*)(ws + (10u << 20));          // 2MB
  int* win = (int*)(ws + (12u << 20));                      // 2MB
  ushort_t* wt = (ushort_t*)(ws + (14u << 20));             // 256KB
  float* me0 = (float*)(ws + (14u << 20) + (256u << 10));   // 256KB
  float* me1 = (float*)(ws + (14u << 20) + (512u << 10));   // 256KB
  unsigned* recs = (unsigned*)(ws + (15u << 20));           // 256KB
  int* dcnt = (int*)(ws + (15u << 20) + (256u << 10));      // 16KB
  int* rowptr = (int*)(ws + (15u << 20) + (272u << 10));    // 16KB+4
  unsigned* aggkB = (unsigned*)(ws + (16u << 20));          // 2MB
  ushort_t* wo = (ushort_t*)(ws + (18u << 20));             // 384KB
  ushort_t* wm = (ushort_t*)(ws + (18u << 20) + (512u << 10));  // 512KB

  k_wprep_all<<<2176, 256, 0, stream>>>(W_h1, W_h2, W_o1, W_o2, W_m1, W_m2,
                                        bond_tab, W_me, b_me, b_mg,
                                        wt, wo, wm, win, me0, me1, aggkA, aggkB);
  k_pre2<<<512, 256, 0, stream>>>(x, atom_tab, wm, b_m1, b_m2,
                                  nf, hidA, m1, m2, eidx32, win);
  k_dcount<<<2048, 256, 0, stream>>>(win, dcnt);
  k_dscan<<<1, 512, 0, stream>>>(dcnt, rowptr);
  k_dfill<<<2048, 256, 0, stream>>>(win, eattr, rowptr, recs);

  int* cnt = rowptr + 4096;   // total edge count written by k_dscan

  // layer 0
  k_edge<<<1024, 512, 0, stream>>>(recs, cnt, m1, m2, me0,
                                   wt + 0 * 16384, wt + 1 * 16384,
                                   wt + 2 * 16384, wt + 3 * 16384,
                                   b_h1, b_h2, aggkA);
  k_out_m12<<<256, 256, 0, stream>>>(nf, hidA, aggkA,
                                     wo + 0 * 49152, wo + 1 * 49152,
                                     b_o1, b_o2,
                                     wm + 131072, b_m1 + Hh, b_m2 + Hh,
                                     hidB, m1, m2);
  // layer 1
  k_edge<<<1024, 512, 0, stream>>>(recs, cnt, m1, m2, me1,
                                   wt + 4 * 16384, wt + 5 * 16384,
                                   wt + 6 * 16384, wt + 7 * 16384,
                                   b_h1 + Hh, b_h2 + Hh, aggkB);
  k_out<<<256, 256, 0, stream>>>(nf, hidB, aggkB,
                                 wo + 2 * 49152, wo + 3 * 49152,
                                 b_o1 + Hh, b_o2 + Hh, hidA);
  k_head<<<32, 128, 0, stream>>>(hidA, Wg1, bg1, Wg2, bg2, out);
}

// Round 18
// 111.071 us; speedup vs baseline: 1.0377x; 1.0377x over previous
//
#include <hip/hip_runtime.h>

#define Gg   32
#define Nn   128
#define Hh   128
#define Ee   65536
#define GN   4096      // Gg*Nn
#define GNN  524288    // Gg*Nn*Nn

typedef unsigned short ushort_t;
typedef __attribute__((ext_vector_type(8))) __bf16 bf16x8;
typedef __attribute__((ext_vector_type(4))) float f32x4;
struct us4 { ushort_t a, b, c, d; };

__device__ __forceinline__ float reluf(float x) { return x > 0.f ? x : 0.f; }

// monotone float <-> u32 key (for atomicMax on floats incl. negatives)
__device__ __forceinline__ unsigned fkey(float f) {
  unsigned u = __float_as_uint(f);
  return (u & 0x80000000u) ? ~u : (u | 0x80000000u);
}
__device__ __forceinline__ float funkey(unsigned k) {
  unsigned u = (k & 0x80000000u) ? (k ^ 0x80000000u) : ~k;
  return __uint_as_float(u);
}

// round-to-nearest-even f32 -> bf16 bits
__device__ __forceinline__ ushort_t bfh(float x) {
  unsigned u = __float_as_uint(x);
  return (ushort_t)((u + 0x7FFFu + ((u >> 16) & 1u)) >> 16);
}
__device__ __forceinline__ void split2(float x, ushort_t& h, ushort_t& l) {
  h = bfh(x);
  float hf = __uint_as_float(((unsigned)h) << 16);
  l = bfh(x - hf);
}

// ---------------- phase 1: weight prep (wt+wo+wm) + win fill + me2, ONE launch --
// fragment order: element (n,k): nf=n>>4, lr=n&15, kf=k>>5, lg=(k>>3)&3, j=k&7
// off = ((nf*KCH + kf)*64 + lg*16 + lr)*8 + j
__global__ __launch_bounds__(256) void k_wprep_all(const float* __restrict__ W_h1,
                                                   const float* __restrict__ W_h2,
                                                   const float* __restrict__ W_o1,
                                                   const float* __restrict__ W_o2,
                                                   const float* __restrict__ W_m1,
                                                   const float* __restrict__ W_m2,
                                                   const float* __restrict__ bond_tab,
                                                   const float* __restrict__ W_me,
                                                   const float* __restrict__ b_me,
                                                   const float* __restrict__ b_mg,
                                                   ushort_t* __restrict__ wt,
                                                   ushort_t* __restrict__ wo,
                                                   ushort_t* __restrict__ wm,
                                                   int* __restrict__ win,
                                                   float* __restrict__ me0,
                                                   float* __restrict__ me1,
                                                   unsigned* __restrict__ aggkA,
                                                   unsigned* __restrict__ aggkB) {
  int b = blockIdx.x;
  int tid = threadIdx.x;
  if (b < 256) {                       // wt: 2l*2m*16384, KCH=4
    int t = b * 256 + tid;
    int l = t >> 15;
    int m = (t >> 14) & 1;
    int e = t & 16383;
    int n = e & 127, k = e >> 7;
    const float* W = (m == 0 ? W_h1 : W_h2) + l * 16384;
    float v = W[k * 128 + n];
    ushort_t h, lo;
    split2(v, h, lo);
    int nf = n >> 4, lr = n & 15, kf = k >> 5, lg = (k >> 3) & 3, j = k & 7;
    int off = ((nf * 4 + kf) * 64 + lg * 16 + lr) * 8 + j;
    int base = ((l * 2 + m) * 2) * 16384;
    wt[base + off] = h;
    wt[base + 16384 + off] = lo;
  } else if (b < 640) {                // wo: 2l*49152, KCH=12
    int ep = (b - 256) * 256 + tid;
    int l = (ep >= 49152) ? 1 : 0;
    int e = ep - l * 49152;
    int n = e / 384, k = e - n * 384;
    float v = (k < 256) ? W_o1[(l * 256 + k) * 128 + n]
                        : W_o2[(l * 128 + (k - 256)) * 128 + n];
    ushort_t h, lo;
    split2(v, h, lo);
    int nf = n >> 4, lr = n & 15, kf = k >> 5, lg = (k >> 3) & 3, j = k & 7;
    int off = ((nf * 12 + kf) * 64 + lg * 16 + lr) * 8 + j;
    wo[(l * 2 + 0) * 49152 + off] = h;
    wo[(l * 2 + 1) * 49152 + off] = lo;
  } else if (b < 1152) {               // wm: 2l*2m*32768, KCH=8
    int t = (b - 640) * 256 + tid;
    int l = t >> 16;
    int m = (t >> 15) & 1;
    int e = t & 32767;
    int n = e >> 8, k = e & 255;
    const float* W = (m == 0 ? W_m1 : W_m2);
    float v = W[(l * 256 + k) * 128 + n];
    ushort_t h, lo;
    split2(v, h, lo);
    int nf = n >> 4, lr = n & 15, kf = k >> 5, lg = (k >> 3) & 3, j = k & 7;
    int off = ((nf * 8 + kf) * 64 + lg * 16 + lr) * 8 + j;
    int base = ((l * 2 + m) * 2) * 32768;
    wm[base + off] = h;
    wm[base + 32768 + off] = lo;
  } else if (b < 1664) {               // win = -1 (131072 int4s = 2MB)
    int idx = (b - 1152) * 256 + tid;
    ((int4*)win)[idx] = make_int4(-1, -1, -1, -1);
  } else {                             // me tables + aggk inits (512 blocks)
    int bx = b - 1664;
    int l = bx >> 8, b2 = bx & 255;
    const float* W = W_me + l * 16384;
    const float* bme = b_me + l * 128;
    const float* bmg = b_mg + l * 128;
    float* me = l ? me1 : me0;
    unsigned* aggk = l ? aggkB : aggkA;
    __shared__ float v[2][128];
    int half = tid >> 7, j = tid & 127;
    int c = b2 * 2 + half;
    int a0 = c & 7, a1 = (c >> 3) & 7, a2 = (c >> 6) & 7;
    v[half][j] = bond_tab[a0 * 128 + j] + bond_tab[(8 + a1) * 128 + j] +
                 bond_tab[(16 + a2) * 128 + j];
    __syncthreads();
    float acc = bme[j] + bmg[j];
    for (int i = 0; i < 128; ++i) acc += v[half][i] * W[i * 128 + j];
    me[c * 128 + j] = acc;
    unsigned key = fkey(-1.0e9f);
#pragma unroll
    for (int i = 0; i < 8; ++i) aggk[b2 * 2048 + i * 256 + tid] = key;
  }
}

// ---------------- MFMA A-fragment helpers ----------------
__device__ __forceinline__ void load_afrag(const ushort_t (*MH)[136],
                                           const ushort_t (*ML)[136],
                                           int row, int lg,
                                           bf16x8 ah[4], bf16x8 al[4]) {
#pragma unroll
  for (int kf = 0; kf < 4; ++kf) {
    ah[kf] = *(const bf16x8*)&MH[row][lg * 8 + 32 * kf];
    al[kf] = *(const bf16x8*)&ML[row][lg * 8 + 32 * kf];
  }
}

__device__ __forceinline__ void load_afrag264(const ushort_t (*MH)[264],
                                              const ushort_t (*ML)[264],
                                              int row, int base, int lg,
                                              bf16x8 ah[4], bf16x8 al[4]) {
#pragma unroll
  for (int kf = 0; kf < 4; ++kf) {
    ah[kf] = *(const bf16x8*)&MH[row][base + lg * 8 + 32 * kf];
    al[kf] = *(const bf16x8*)&ML[row][base + lg * 8 + 32 * kf];
  }
}

// ---------------- phase 2: node-encode+m12 (b<256) + edge scatter (b>=256) ------
__global__ __launch_bounds__(256) void k_pre2(const int* __restrict__ x,
                                              const float* __restrict__ atom_tab,
                                              const ushort_t* __restrict__ wm,
                                              const float* __restrict__ bi1,
                                              const float* __restrict__ bi2,
                                              float* __restrict__ nf_,
                                              float* __restrict__ hid,
                                              float* __restrict__ m1,
                                              float* __restrict__ m2,
                                              const int* __restrict__ e32,
                                              int* __restrict__ win) {
  int b = blockIdx.x;
  int tid = threadIdx.x;
  if (b >= 256) {                     // ---- edge winner scatter ----
    __shared__ int sflag;
    if (tid == 0) sflag = 0;
    __syncthreads();
    if (tid < 128 && e32[2 * tid + 1] != 0) atomicOr(&sflag, 1);
    __syncthreads();
    int e = (b - 256) * 256 + tid;
    int sg, dg;
    if (sflag) { sg = e32[e]; dg = e32[Ee + e]; }        // int32 layout
    else       { sg = e32[2 * e]; dg = e32[2 * Ee + 2 * e]; }  // int64 low words
    int g = sg / Nn;
    int s = sg % Nn;
    int d = dg % Nn;
    atomicMax(&win[(g * Nn + d) * Nn + s], e);   // destination-major
    return;
  }
  // ---- node encode + layer-0 m12 (hid0=0 => seg0 only) ----
  __shared__ ushort_t AH[16][136];
  __shared__ ushort_t AL[16][136];
  __shared__ int xs[144];
  int v0 = b * 16;
  if (tid < 144) xs[tid] = x[v0 * 9 + tid];
  __syncthreads();
#pragma unroll
  for (int i = 0; i < 8; ++i) {
    int e = tid + i * 256;
    int row = e >> 7, col = e & 127;
    float s = 0.f;
#pragma unroll
    for (int f = 0; f < 9; ++f) {
      int idx = xs[row * 9 + f];
      s += atom_tab[(f * 119 + idx) * Hh + col];
    }
    nf_[(v0 + row) * Hh + col] = s;
    hid[(v0 + row) * Hh + col] = 0.f;
    ushort_t h, l;
    split2(s, h, l);
    AH[row][col] = h;
    AL[row][col] = l;
  }
  __syncthreads();
  int lane = tid & 63, wid = tid >> 6;
  int lr = lane & 15, lg = lane >> 4;
  f32x4 a1[2], a2[2];
#pragma unroll
  for (int i = 0; i < 2; ++i) { a1[i] = (f32x4){0.f,0.f,0.f,0.f}; a2[i] = (f32x4){0.f,0.f,0.f,0.f}; }
  const ushort_t* w1h = wm;
  const ushort_t* w1l = wm + 32768;
  const ushort_t* w2h = wm + 65536;
  const ushort_t* w2l = wm + 98304;
  bf16x8 ah[4], al[4];
  load_afrag(AH, AL, lr, lg, ah, al);
#pragma unroll
  for (int jj = 0; jj < 2; ++jj) {
    int nfr = 2 * wid + jj;
#pragma unroll
    for (int kf = 0; kf < 4; ++kf) {            // seg 0 only (hid = 0)
      int ch = ((nfr * 8 + kf) << 9) + lane * 8;
      bf16x8 b1h = *(const bf16x8*)(w1h + ch);
      bf16x8 b1l = *(const bf16x8*)(w1l + ch);
      bf16x8 b2h = *(const bf16x8*)(w2h + ch);
      bf16x8 b2l = *(const bf16x8*)(w2l + ch);
      a1[jj] = __builtin_amdgcn_mfma_f32_16x16x32_bf16(ah[kf], b1h, a1[jj], 0, 0, 0);
      a1[jj] = __builtin_amdgcn_mfma_f32_16x16x32_bf16(ah[kf], b1l, a1[jj], 0, 0, 0);
      a1[jj] = __builtin_amdgcn_mfma_f32_16x16x32_bf16(al[kf], b1h, a1[jj], 0, 0, 0);
      a2[jj] = __builtin_amdgcn_mfma_f32_16x16x32_bf16(ah[kf], b2h, a2[jj], 0, 0, 0);
      a2[jj] = __builtin_amdgcn_mfma_f32_16x16x32_bf16(ah[kf], b2l, a2[jj], 0, 0, 0);
      a2[jj] = __builtin_amdgcn_mfma_f32_16x16x32_bf16(al[kf], b2h, a2[jj], 0, 0, 0);
    }
  }
#pragma unroll
  for (int jj = 0; jj < 2; ++jj) {
    int col = 16 * (2 * wid + jj) + lr;
    float bb1 = bi1[col], bb2 = bi2[col];
#pragma unroll
    for (int reg = 0; reg < 4; ++reg) {
      int row = v0 + lg * 4 + reg;
      m1[row * Hh + col] = a1[jj][reg] + bb1;
      m2[row * Hh + col] = a2[jj][reg] + bb2;
    }
  }
}

// ---------------- per-destination compaction: count / scan / fill ----------------
__global__ __launch_bounds__(256) void k_dcount(const int* __restrict__ win,
                                                int* __restrict__ dcnt) {
  int tid = threadIdx.x;
  int grp = tid >> 7, t = tid & 127;
  int dest = blockIdx.x * 2 + grp;
  bool valid = win[dest * 128 + t] >= 0;
  unsigned long long mask = __ballot(valid);
  __shared__ int cw[4];
  if ((tid & 63) == 0) cw[tid >> 6] = __popcll(mask);
  __syncthreads();
  if (t == 0) dcnt[dest] = cw[grp * 2] + cw[grp * 2 + 1];
}

__global__ __launch_bounds__(512) void k_dscan(const int* __restrict__ dcnt,
                                               int* __restrict__ rowptr) {
  int tid = threadIdx.x;            // 512 threads x 8 dests = 4096
  int c0, c1, c2, c3, c4, c5, c6, c7;
  int bi = tid * 8;
  c0 = dcnt[bi + 0]; c1 = dcnt[bi + 1]; c2 = dcnt[bi + 2]; c3 = dcnt[bi + 3];
  c4 = dcnt[bi + 4]; c5 = dcnt[bi + 5]; c6 = dcnt[bi + 6]; c7 = dcnt[bi + 7];
  int s = c0 + c1 + c2 + c3 + c4 + c5 + c6 + c7;
  int x = s;
#pragma unroll
  for (int off = 1; off < 64; off <<= 1) {
    int y = __shfl_up(x, off, 64);
    if ((tid & 63) >= off) x += y;
  }
  __shared__ int wsum[8], woff[8];
  if ((tid & 63) == 63) wsum[tid >> 6] = x;
  __syncthreads();
  if (tid == 0) {
    int a = 0;
#pragma unroll
    for (int i = 0; i < 8; ++i) { woff[i] = a; a += wsum[i]; }
  }
  __syncthreads();
  int base = x - s + woff[tid >> 6];
  rowptr[bi + 0] = base; base += c0;
  rowptr[bi + 1] = base; base += c1;
  rowptr[bi + 2] = base; base += c2;
  rowptr[bi + 3] = base; base += c3;
  rowptr[bi + 4] = base; base += c4;
  rowptr[bi + 5] = base; base += c5;
  rowptr[bi + 6] = base; base += c6;
  rowptr[bi + 7] = base; base += c7;
  if (tid == 511) rowptr[4096] = base;   // total count
}

__global__ __launch_bounds__(256) void k_dfill(const int* __restrict__ win,
                                               const int* __restrict__ eattr,
                                               const int* __restrict__ rowptr,
                                               unsigned* __restrict__ recs) {
  int tid = threadIdx.x;
  int grp = tid >> 7, t = tid & 127;
  int dest = blockIdx.x * 2 + grp;
  int e = win[dest * 128 + t];
  bool valid = e >= 0;
  unsigned long long mask = __ballot(valid);
  __shared__ int cw[4];
  int lane = tid & 63;
  if (lane == 0) cw[tid >> 6] = __popcll(mask);
  __syncthreads();
  if (valid) {
    int off = __popcll(mask & ((1ull << lane) - 1));
    if ((tid >> 6) & 1) off += cw[grp * 2];
    int a0 = eattr[e * 3 + 0], a1 = eattr[e * 3 + 1], a2 = eattr[e * 3 + 2];
    unsigned code = (unsigned)(a0 + (a1 << 3) + (a2 << 6));
    unsigned idx = ((unsigned)dest << 7) | (unsigned)t;   // (g*128+d)*128+s
    recs[rowptr[dest] + off] = (idx << 9) | code;         // sorted by dest
  }
}

// ---------------- edge phase: 64-edge tile, 8 waves (1 col-group each) ----------
__global__ __launch_bounds__(512) void k_edge(const unsigned* __restrict__ recs,
                                              const int* __restrict__ cnt,
                                              const float* __restrict__ m1,
                                              const float* __restrict__ m2,
                                              const float* __restrict__ me,
                                              const ushort_t* __restrict__ wt1h,
                                              const ushort_t* __restrict__ wt1l,
                                              const ushort_t* __restrict__ wt2h,
                                              const ushort_t* __restrict__ wt2l,
                                              const float* __restrict__ b_h1,
                                              const float* __restrict__ b_h2,
                                              unsigned* __restrict__ aggk) {
  __shared__ ushort_t MH[64][136];
  __shared__ ushort_t ML[64][136];
  __shared__ unsigned srec[64];
  int tid = threadIdx.x;
  int n = *cnt;
  if (tid < 64) {
    int r = blockIdx.x * 64 + tid;
    srec[tid] = (r < n) ? recs[r] : 0xFFFFFFFFu;
  }
  __syncthreads();
  // build M tile (float4-vectorized; 512 threads cover 64 rows x 32 col4)
  {
    int c4 = tid & 31, rq = tid >> 5;     // rq in 0..15
#pragma unroll
    for (int i = 0; i < 4; ++i) {
      int r = 16 * i + rq;
      float4 v = make_float4(0.f, 0.f, 0.f, 0.f);
      unsigned rec = srec[r];
      if (rec != 0xFFFFFFFFu) {
        int code = rec & 511;
        unsigned idx = rec >> 9;
        int s = idx & 127, d = (idx >> 7) & 127, g = idx >> 14;
        float4 a = *(const float4*)(m1 + (((g << 7) + d) << 7) + c4 * 4);
        float4 b = *(const float4*)(m2 + (((g << 7) + s) << 7) + c4 * 4);
        float4 cme = *(const float4*)(me + (code << 7) + c4 * 4);
        v.x = reluf(a.x + b.x + cme.x);
        v.y = reluf(a.y + b.y + cme.y);
        v.z = reluf(a.z + b.z + cme.z);
        v.w = reluf(a.w + b.w + cme.w);
      }
      us4 h4, l4;
      split2(v.x, h4.a, l4.a); split2(v.y, h4.b, l4.b);
      split2(v.z, h4.c, l4.c); split2(v.w, h4.d, l4.d);
      *(us4*)&MH[r][c4 * 4] = h4;
      *(us4*)&ML[r][c4 * 4] = l4;
    }
  }
  __syncthreads();

  int lane = tid & 63, wid = tid >> 6;     // wid = nf (0..7)
  int lr = lane & 15, lg = lane >> 4;
  float b1v = b_h1[16 * wid + lr];
  float b2v = b_h2[16 * wid + lr];
  f32x4 acc[4];
#pragma unroll
  for (int rg = 0; rg < 4; ++rg) acc[rg] = (f32x4){0.f, 0.f, 0.f, 0.f};
  // GEMM1: wave computes all 64 rows x its 16 cols (nf = wid)
#pragma unroll
  for (int rg = 0; rg < 4; ++rg) {
    bf16x8 ah[4], al[4];
    load_afrag(MH, ML, 16 * rg + lr, lg, ah, al);
#pragma unroll
    for (int kf = 0; kf < 4; ++kf) {
      int ch = ((wid * 4 + kf) << 9) + lane * 8;
      bf16x8 bh = *(const bf16x8*)(wt1h + ch);
      bf16x8 bl = *(const bf16x8*)(wt1l + ch);
      acc[rg] = __builtin_amdgcn_mfma_f32_16x16x32_bf16(ah[kf], bh, acc[rg], 0, 0, 0);
      acc[rg] = __builtin_amdgcn_mfma_f32_16x16x32_bf16(ah[kf], bl, acc[rg], 0, 0, 0);
      acc[rg] = __builtin_amdgcn_mfma_f32_16x16x32_bf16(al[kf], bh, acc[rg], 0, 0, 0);
    }
  }
  __syncthreads();   // M fully consumed by all waves
  // T = relu(acc + b1) -> MH/ML
#pragma unroll
  for (int rg = 0; rg < 4; ++rg)
#pragma unroll
    for (int reg = 0; reg < 4; ++reg) {
      float t = reluf(acc[rg][reg] + b1v);
      int row = 16 * rg + lg * 4 + reg;
      int col = 16 * wid + lr;
      ushort_t h, l;
      split2(t, h, l);
      MH[row][col] = h;
      ML[row][col] = l;
    }
  __syncthreads();   // T complete
  // GEMM2
#pragma unroll
  for (int rg = 0; rg < 4; ++rg) acc[rg] = (f32x4){0.f, 0.f, 0.f, 0.f};
#pragma unroll
  for (int rg = 0; rg < 4; ++rg) {
    bf16x8 ah[4], al[4];
    load_afrag(MH, ML, 16 * rg + lr, lg, ah, al);
#pragma unroll
    for (int kf = 0; kf < 4; ++kf) {
      int ch = ((wid * 4 + kf) << 9) + lane * 8;
      bf16x8 bh = *(const bf16x8*)(wt2h + ch);
      bf16x8 bl = *(const bf16x8*)(wt2l + ch);
      acc[rg] = __builtin_amdgcn_mfma_f32_16x16x32_bf16(ah[kf], bh, acc[rg], 0, 0, 0);
      acc[rg] = __builtin_amdgcn_mfma_f32_16x16x32_bf16(ah[kf], bl, acc[rg], 0, 0, 0);
      acc[rg] = __builtin_amdgcn_mfma_f32_16x16x32_bf16(al[kf], bh, acc[rg], 0, 0, 0);
    }
  }
  __syncthreads();   // T fully consumed
  // park f32 result bits in MH/ML
#pragma unroll
  for (int rg = 0; rg < 4; ++rg)
#pragma unroll
    for (int reg = 0; reg < 4; ++reg) {
      int row = 16 * rg + lg * 4 + reg;
      int col = 16 * wid + lr;
      unsigned b = __float_as_uint(acc[rg][reg] + b2v);
      MH[row][col] = (ushort_t)(b >> 16);
      ML[row][col] = (ushort_t)(b & 0xFFFFu);
    }
  __syncthreads();
  // run-dedup scatter: rows sorted by (g,d); one atomic per run per col
  {
    int c = tid & 127, quarter = tid >> 7;   // 4 x 16-row segments
    int rbeg = quarter * 16, rend = rbeg + 16;
    unsigned curkey = 0xFFFFu;
    float best = -3.0e38f;
    for (int r = rbeg; r < rend; ++r) {
      unsigned rec = srec[r];
      unsigned key = rec >> 16;   // g*128+d (<=0xFFF) or 0xFFFF if invalid
      if (key != curkey) {
        if (curkey != 0xFFFFu)
          atomicMax(aggk + (curkey << 7) + c, fkey(best));
        curkey = key;
        best = -3.0e38f;
      }
      if (key != 0xFFFFu) {
        unsigned b = ((unsigned)MH[r][c] << 16) | (unsigned)ML[r][c];
        best = fmaxf(best, __uint_as_float(b));
      }
    }
    if (curkey != 0xFFFFu)
      atomicMax(aggk + (curkey << 7) + c, fkey(best));
  }
}

// ---------------- hid update via MFMA (plain, for last layer) ----------------
__global__ __launch_bounds__(256) void k_out(const float* __restrict__ nf,
                                             const float* __restrict__ hid,
                                             const unsigned* __restrict__ aggk,
                                             const ushort_t* __restrict__ wo_h,
                                             const ushort_t* __restrict__ wo_l,
                                             const float* __restrict__ bo1,
                                             const float* __restrict__ bo2,
                                             float* __restrict__ hidn) {
  __shared__ ushort_t MH[16][136];
  __shared__ ushort_t ML[16][136];
  int tid = threadIdx.x;
  int v0 = blockIdx.x * 16;
  int lane = tid & 63, wid = tid >> 6;
  int lr = lane & 15, lg = lane >> 4;
  f32x4 acc[2];
#pragma unroll
  for (int jj = 0; jj < 2; ++jj) acc[jj] = (f32x4){0.f, 0.f, 0.f, 0.f};

  for (int seg = 0; seg < 3; ++seg) {
#pragma unroll
    for (int i = 0; i < 2; ++i) {
      int idx = tid + i * 256;        // over 512 float4s
      int row = idx >> 5, c4 = idx & 31;
      float4 v;
      if (seg == 0)      v = ((const float4*)nf)[(v0 + row) * 32 + c4];
      else if (seg == 1) v = ((const float4*)hid)[(v0 + row) * 32 + c4];
      else {
        uint4 k4 = ((const uint4*)aggk)[(v0 + row) * 32 + c4];
        v.x = funkey(k4.x); v.y = funkey(k4.y); v.z = funkey(k4.z); v.w = funkey(k4.w);
      }
      us4 h4, l4;
      split2(v.x, h4.a, l4.a);
      split2(v.y, h4.b, l4.b);
      split2(v.z, h4.c, l4.c);
      split2(v.w, h4.d, l4.d);
      *(us4*)&MH[row][c4 * 4] = h4;
      *(us4*)&ML[row][c4 * 4] = l4;
    }
    __syncthreads();
    bf16x8 ah[4], al[4];
    load_afrag(MH, ML, lr, lg, ah, al);
#pragma unroll
    for (int jj = 0; jj < 2; ++jj) {
      int nfr = 2 * wid + jj;
#pragma unroll
      for (int kf = 0; kf < 4; ++kf) {
        int ch = ((nfr * 12 + seg * 4 + kf) << 9) + lane * 8;
        bf16x8 bh = *(const bf16x8*)(wo_h + ch);
        bf16x8 bl = *(const bf16x8*)(wo_l + ch);
        acc[jj] = __builtin_amdgcn_mfma_f32_16x16x32_bf16(ah[kf], bh, acc[jj], 0, 0, 0);
        acc[jj] = __builtin_amdgcn_mfma_f32_16x16x32_bf16(ah[kf], bl, acc[jj], 0, 0, 0);
        acc[jj] = __builtin_amdgcn_mfma_f32_16x16x32_bf16(al[kf], bh, acc[jj], 0, 0, 0);
      }
    }
    __syncthreads();
  }
#pragma unroll
  for (int jj = 0; jj < 2; ++jj) {
    int col = 16 * (2 * wid + jj) + lr;
    float b = bo1[col] + bo2[col];
#pragma unroll
    for (int reg = 0; reg < 4; ++reg)
      hidn[(v0 + lg * 4 + reg) * Hh + col] = reluf(acc[jj][reg] + b);
  }
}

// ---------------- hid update + next-layer m12 fused (for layer transition) -----
__global__ __launch_bounds__(256) void k_out_m12(const float* __restrict__ nf,
                                                 const float* __restrict__ hid,
                                                 const unsigned* __restrict__ aggk,
                                                 const ushort_t* __restrict__ wo_h,
                                                 const ushort_t* __restrict__ wo_l,
                                                 const float* __restrict__ bo1,
                                                 const float* __restrict__ bo2,
                                                 const ushort_t* __restrict__ wm,
                                                 const float* __restrict__ bm1,
                                                 const float* __restrict__ bm2,
                                                 float* __restrict__ hidn,
                                                 float* __restrict__ m1,
                                                 float* __restrict__ m2) {
  __shared__ ushort_t AH[16][264];
  __shared__ ushort_t AL[16][264];
  int tid = threadIdx.x;
  int v0 = blockIdx.x * 16;
  int lane = tid & 63, wid = tid >> 6;
  int lr = lane & 15, lg = lane >> 4;
  f32x4 acc[2];
#pragma unroll
  for (int jj = 0; jj < 2; ++jj) acc[jj] = (f32x4){0.f, 0.f, 0.f, 0.f};

  // phase 1: hidn = relu([nf|hid|agg] @ Wo + b)
  for (int seg = 0; seg < 3; ++seg) {
#pragma unroll
    for (int i = 0; i < 2; ++i) {
      int idx = tid + i * 256;
      int row = idx >> 5, c4 = idx & 31;
      float4 v;
      if (seg == 0)      v = ((const float4*)nf)[(v0 + row) * 32 + c4];
      else if (seg == 1) v = ((const float4*)hid)[(v0 + row) * 32 + c4];
      else {
        uint4 k4 = ((const uint4*)aggk)[(v0 + row) * 32 + c4];
        v.x = funkey(k4.x); v.y = funkey(k4.y); v.z = funkey(k4.z); v.w = funkey(k4.w);
      }
      us4 h4, l4;
      split2(v.x, h4.a, l4.a);
      split2(v.y, h4.b, l4.b);
      split2(v.z, h4.c, l4.c);
      split2(v.w, h4.d, l4.d);
      *(us4*)&AH[row][c4 * 4] = h4;
      *(us4*)&AL[row][c4 * 4] = l4;
    }
    __syncthreads();
    bf16x8 ah[4], al[4];
    load_afrag264(AH, AL, lr, 0, lg, ah, al);
#pragma unroll
    for (int jj = 0; jj < 2; ++jj) {
      int nfr = 2 * wid + jj;
#pragma unroll
      for (int kf = 0; kf < 4; ++kf) {
        int ch = ((nfr * 12 + seg * 4 + kf) << 9) + lane * 8;
        bf16x8 bh = *(const bf16x8*)(wo_h + ch);
        bf16x8 bl = *(const bf16x8*)(wo_l + ch);
        acc[jj] = __builtin_amdgcn_mfma_f32_16x16x32_bf16(ah[kf], bh, acc[jj], 0, 0, 0);
        acc[jj] = __builtin_amdgcn_mfma_f32_16x16x32_bf16(ah[kf], bl, acc[jj], 0, 0, 0);
        acc[jj] = __builtin_amdgcn_mfma_f32_16x16x32_bf16(al[kf], bh, acc[jj], 0, 0, 0);
      }
    }
    __syncthreads();
  }
  // write hidn + stage hidn into cols 128..255
#pragma unroll
  for (int jj = 0; jj < 2; ++jj) {
    int col = 16 * (2 * wid + jj) + lr;
    float b = bo1[col] + bo2[col];
#pragma unroll
    for (int reg = 0; reg < 4; ++reg) {
      float hv = reluf(acc[jj][reg] + b);
      int row = lg * 4 + reg;
      hidn[(v0 + row) * Hh + col] = hv;
      ushort_t h, l;
      split2(hv, h, l);
      AH[row][128 + col] = h;
      AL[row][128 + col] = l;
    }
  }
  // stage nf into cols 0..127
#pragma unroll
  for (int i = 0; i < 2; ++i) {
    int idx = tid + i * 256;
    int row = idx >> 5, c4 = idx & 31;
    float4 v = ((const float4*)nf)[(v0 + row) * 32 + c4];
    us4 h4, l4;
    split2(v.x, h4.a, l4.a);
    split2(v.y, h4.b, l4.b);
    split2(v.z, h4.c, l4.c);
    split2(v.w, h4.d, l4.d);
    *(us4*)&AH[row][c4 * 4] = h4;
    *(us4*)&AL[row][c4 * 4] = l4;
  }
  __syncthreads();
  // phase 2: m1/m2 = [nf|hidn] @ W_m + b (2 segs)
  f32x4 a1[2], a2[2];
#pragma unroll
  for (int i = 0; i < 2; ++i) { a1[i] = (f32x4){0.f,0.f,0.f,0.f}; a2[i] = (f32x4){0.f,0.f,0.f,0.f}; }
  const ushort_t* w1h = wm;
  const ushort_t* w1l = wm + 32768;
  const ushort_t* w2h = wm + 65536;
  const ushort_t* w2l = wm + 98304;
#pragma unroll
  for (int seg = 0; seg < 2; ++seg) {
    bf16x8 ah[4], al[4];
    load_afrag264(AH, AL, lr, seg * 128, lg, ah, al);
#pragma unroll
    for (int jj = 0; jj < 2; ++jj) {
      int nfr = 2 * wid + jj;
#pragma unroll
      for (int kf = 0; kf < 4; ++kf) {
        int ch = ((nfr * 8 + seg * 4 + kf) << 9) + lane * 8;
        bf16x8 b1h = *(const bf16x8*)(w1h + ch);
        bf16x8 b1l = *(const bf16x8*)(w1l + ch);
        bf16x8 b2h = *(const bf16x8*)(w2h + ch);
        bf16x8 b2l = *(const bf16x8*)(w2l + ch);
        a1[jj] = __builtin_amdgcn_mfma_f32_16x16x32_bf16(ah[kf], b1h, a1[jj], 0, 0, 0);
        a1[jj] = __builtin_amdgcn_mfma_f32_16x16x32_bf16(ah[kf], b1l, a1[jj], 0, 0, 0);
        a1[jj] = __builtin_amdgcn_mfma_f32_16x16x32_bf16(al[kf], b1h, a1[jj], 0, 0, 0);
        a2[jj] = __builtin_amdgcn_mfma_f32_16x16x32_bf16(ah[kf], b2h, a2[jj], 0, 0, 0);
        a2[jj] = __builtin_amdgcn_mfma_f32_16x16x32_bf16(ah[kf], b2l, a2[jj], 0, 0, 0);
        a2[jj] = __builtin_amdgcn_mfma_f32_16x16x32_bf16(al[kf], b2h, a2[jj], 0, 0, 0);
      }
    }
  }
#pragma unroll
  for (int jj = 0; jj < 2; ++jj) {
    int col = 16 * (2 * wid + jj) + lr;
    float bb1 = bm1[col], bb2 = bm2[col];
#pragma unroll
    for (int reg = 0; reg < 4; ++reg) {
      int row = v0 + lg * 4 + reg;
      m1[row * Hh + col] = a1[jj][reg] + bb1;
      m2[row * Hh + col] = a2[jj][reg] + bb2;
    }
  }
}

// ---------------- readout head ----------------
__global__ __launch_bounds__(128) void k_head(const float* __restrict__ hid,
                                              const float* __restrict__ Wg1,
                                              const float* __restrict__ bg1,
                                              const float* __restrict__ Wg2,
                                              const float* __restrict__ bg2,
                                              float* __restrict__ out) {
  __shared__ float emb[Hh];
  __shared__ float tt[Hh];
  int g = blockIdx.x, j = threadIdx.x;
  float s = 0.f;
  for (int n = 0; n < Nn; ++n) s += hid[(g * Nn + n) * Hh + j];
  emb[j] = s * (1.f / Nn);
  __syncthreads();
  float a = bg1[j];
  for (int i = 0; i < Hh; ++i) a += emb[i] * Wg1[i * Hh + j];
  tt[j] = reluf(a);
  __syncthreads();
  if (j < 12) {
    float o = bg2[j];
    for (int i = 0; i < Hh; ++i) o += tt[i] * Wg2[i * 12 + j];
    out[g * 12 + j] = o;
  }
}

extern "C" void kernel_launch(void* const* d_in, const int* in_sizes, int n_in,
                              void* d_out, int out_size, void* d_ws, size_t ws_size,
                              hipStream_t stream) {
  const int* x = (const int*)d_in[0];
  const int* eidx32 = (const int*)d_in[1];
  const int* eattr = (const int*)d_in[2];
  const float* atom_tab = (const float*)d_in[4];
  const float* bond_tab = (const float*)d_in[5];
  const float* W_m1 = (const float*)d_in[6];
  const float* b_m1 = (const float*)d_in[7];
  const float* W_m2 = (const float*)d_in[8];
  const float* b_m2 = (const float*)d_in[9];
  const float* W_me = (const float*)d_in[10];
  const float* b_me = (const float*)d_in[11];
  const float* b_mg = (const float*)d_in[13];
  const float* W_h1 = (const float*)d_in[14];
  const float* b_h1 = (const float*)d_in[15];
  const float* W_h2 = (const float*)d_in[16];
  const float* b_h2 = (const float*)d_in[17];
  const float* W_o1 = (const float*)d_in[18];
  const float* b_o1 = (const float*)d_in[19];
  const float* W_o2 = (const float*)d_in[20];
  const float* b_o2 = (const float*)d_in[21];
  const float* Wg1 = (const float*)d_in[22];
  const float* bg1 = (const float*)d_in[23];
  const float* Wg2 = (const float*)d_in[24];
  const float* bg2 = (const float*)d_in[25];
  float* out = (float*)d_out;

  char* ws = (char*)d_ws;
  float* nf = (float*)(ws);                                 // 2MB
  float* hidA = (float*)(ws + (2u << 20));                  // 2MB (hid0 zeros, hid2)
  float* hidB = (float*)(ws + (4u << 20));                  // 2MB (hid1)
  float* m1 = (float*)(ws + (6u << 20));                    // 2MB
  float* m2 = (float*)(ws + (8u << 20));                    // 2MB
  unsigned* aggkA = (unsigned*)(ws + (10u << 20));          // 2MB
  int* win = (int*)(ws + (12u << 20));                      // 2MB
  ushort_t* wt = (ushort_t*)(ws + (14u << 20));             // 256KB
  float* me0 = (float*)(ws + (14u << 20) + (256u << 10));   // 256KB
  float* me1 = (float*)(ws + (14u << 20) + (512u << 10));   // 256KB
  unsigned* recs = (unsigned*)(ws + (15u << 20));           // 256KB
  int* dcnt = (int*)(ws + (15u << 20) + (256u << 10));      // 16KB
  int* rowptr = (int*)(ws + (15u << 20) + (272u << 10));    // 16KB+4
  unsigned* aggkB = (unsigned*)(ws + (16u << 20));          // 2MB
  ushort_t* wo = (ushort_t*)(ws + (18u << 20));             // 384KB
  ushort_t* wm = (ushort_t*)(ws + (18u << 20) + (512u << 10));  // 512KB

  k_wprep_all<<<2176, 256, 0, stream>>>(W_h1, W_h2, W_o1, W_o2, W_m1, W_m2,
                                        bond_tab, W_me, b_me, b_mg,
                                        wt, wo, wm, win, me0, me1, aggkA, aggkB);
  k_pre2<<<512, 256, 0, stream>>>(x, atom_tab, wm, b_m1, b_m2,
                                  nf, hidA, m1, m2, eidx32, win);
  k_dcount<<<2048, 256, 0, stream>>>(win, dcnt);
  k_dscan<<<1, 512, 0, stream>>>(dcnt, rowptr);
  k_dfill<<<2048, 256, 0, stream>>>(win, eattr, rowptr, recs);

  int* cnt = rowptr + 4096;   // total edge count written by k_dscan

  // layer 0
  k_edge<<<1024, 512, 0, stream>>>(recs, cnt, m1, m2, me0,
                                   wt + 0 * 16384, wt + 1 * 16384,
                                   wt + 2 * 16384, wt + 3 * 16384,
                                   b_h1, b_h2, aggkA);
  k_out_m12<<<256, 256, 0, stream>>>(nf, hidA, aggkA,
                                     wo + 0 * 49152, wo + 1 * 49152,
                                     b_o1, b_o2,
                                     wm + 131072, b_m1 + Hh, b_m2 + Hh,
                                     hidB, m1, m2);
  // layer 1
  k_edge<<<1024, 512, 0, stream>>>(recs, cnt, m1, m2, me1,
                                   wt + 4 * 16384, wt + 5 * 16384,
                                   wt + 6 * 16384, wt + 7 * 16384,
                                   b_h1 + Hh, b_h2 + Hh, aggkB);
  k_out<<<256, 256, 0, stream>>>(nf, hidB, aggkB,
                                 wo + 2 * 49152, wo + 3 * 49152,
                                 b_o1 + Hh, b_o2 + Hh, hidA);
  k_head<<<32, 128, 0, stream>>>(hidA, Wg1, bg1, Wg2, bg2, out);
}